// Round 1
// baseline (773.211 us; speedup 1.0000x reference)
//
#include <hip/hip_runtime.h>

typedef unsigned short u16;
typedef unsigned int u32;
typedef __attribute__((ext_vector_type(8))) short short8;
typedef __attribute__((ext_vector_type(4))) float floatx4;

#define LOG2PI_F 1.8378770664093453f

// ---------- helpers ----------
__device__ __forceinline__ u16 f2bf(float f) {
  union { float f; u32 i; } c; c.f = f;
  u32 i = c.i;
  u32 r = (i + 0x7fffu + ((i >> 16) & 1u)) >> 16;   // RNE (inputs finite)
  return (u16)r;
}
__device__ __forceinline__ float bf2f(u16 u) {
  union { u32 i; float f; } c; c.i = ((u32)u) << 16; return c.f;
}
__device__ __forceinline__ void llds16(const void* g, void* l) {
  __builtin_amdgcn_global_load_lds(
      (const __attribute__((address_space(1))) u32*)g,
      (__attribute__((address_space(3))) u32*)l, 16, 0, 0);
}
#define SWZ(m, kc) ((kc) ^ (((m) >> 1) & 3))

// ---------- packing kernels ----------
__global__ void pack_xb(const float* __restrict__ in, u16* __restrict__ out, int n4) {
  int i = blockIdx.x * 256 + threadIdx.x;
  if (i >= n4) return;
  const float4 v = ((const float4*)in)[i];
  ushort4 o;
  o.x = f2bf(v.x); o.y = f2bf(v.y); o.z = f2bf(v.z); o.w = f2bf(v.w);
  ((ushort4*)out)[i] = o;
}

// W [K][N] fp32 -> Wt [N][K] bf16
__global__ void pack_wt(const float* __restrict__ W, u16* __restrict__ Wt, int K, int N) {
  int idx = blockIdx.x * 256 + threadIdx.x;
  if (idx >= K * N) return;
  int k = idx / N, n = idx - k * N;
  Wt[(size_t)n * K + k] = f2bf(W[idx]);
}

// W1 [K][N1], W2 [K][N2] fp32 -> Wt [(N1+N2)][K] bf16
__global__ void pack_wt2(const float* __restrict__ W1, const float* __restrict__ W2,
                         u16* __restrict__ Wt, int K, int N1, int N2) {
  int idx = blockIdx.x * 256 + threadIdx.x;
  if (idx >= (N1 + N2) * K) return;
  int n = idx / K, k = idx - n * K;
  float v = (n < N1) ? W1[(size_t)k * N1 + n] : W2[(size_t)k * N2 + (n - N1)];
  Wt[idx] = f2bf(v);
}

__global__ void catf(const float* __restrict__ a, const float* __restrict__ b,
                     float* __restrict__ o, int n1, int n2) {
  int i = blockIdx.x * 256 + threadIdx.x;
  if (i < n1) o[i] = a[i];
  else if (i < n1 + n2) o[i] = b[i - n1];
}

// ---------- MFMA GEMM: C = epi(A @ Bt^T + bias) ----------
// A: [M][K] bf16, Bt: [N][K] bf16, bias: [N] f32
// EPI 0: tanh -> bf16 ; 1: plain -> f32 ; 2: plain -> bf16
template <int EPI>
__global__ __launch_bounds__(256) void gemm_bt(
    const u16* __restrict__ A, const u16* __restrict__ Bt,
    const float* __restrict__ bias, void* __restrict__ Cv,
    int M, int N, int K) {
  __shared__ u16 As[128 * 32];
  __shared__ u16 Bs[128 * 32];
  const int t = threadIdx.x;
  const int wave = t >> 6, lane = t & 63;
  const int quad = lane >> 4, l16 = lane & 15;
  const int bm = blockIdx.x * 128, bn = blockIdx.y * 128;
  const int wm = (wave >> 1) * 64, wn = (wave & 1) * 64;

  floatx4 acc[4][4];
#pragma unroll
  for (int i = 0; i < 4; ++i)
#pragma unroll
    for (int j = 0; j < 4; ++j) acc[i][j] = (floatx4){0.f, 0.f, 0.f, 0.f};

  for (int kt = 0; kt < K; kt += 32) {
    // stage A/B tiles: chunk c covers 8 bf16 (16B); swizzled k-chunk placement
#pragma unroll
    for (int i = 0; i < 2; ++i) {
      int c = i * 256 + t;
      int r = c >> 2, kcS = c & 3;
      int kc = SWZ(r, kcS);
      llds16(A + (size_t)(bm + r) * K + kt + kc * 8, &As[c * 8]);
      llds16(Bt + (size_t)(bn + r) * K + kt + kc * 8, &Bs[c * 8]);
    }
    __builtin_amdgcn_s_waitcnt(0);
    __syncthreads();

    const short8* As8 = (const short8*)As;
    const short8* Bs8 = (const short8*)Bs;
    short8 af[4], bf[4];
#pragma unroll
    for (int mi = 0; mi < 4; ++mi) {
      int m = wm + mi * 16 + l16;
      af[mi] = As8[m * 4 + SWZ(m, quad)];
    }
#pragma unroll
    for (int ni = 0; ni < 4; ++ni) {
      int n = wn + ni * 16 + l16;
      bf[ni] = Bs8[n * 4 + SWZ(n, quad)];
    }
#pragma unroll
    for (int mi = 0; mi < 4; ++mi)
#pragma unroll
      for (int ni = 0; ni < 4; ++ni)
        acc[mi][ni] = __builtin_amdgcn_mfma_f32_16x16x32_bf16(
            af[mi], bf[ni], acc[mi][ni], 0, 0, 0);
    __syncthreads();
  }

  // epilogue: D[row=quad*4+r][col=lane&15]  (m89/m91-verified layout)
#pragma unroll
  for (int ni = 0; ni < 4; ++ni) {
    int col = bn + wn + ni * 16 + l16;
    float bv = bias[col];
#pragma unroll
    for (int mi = 0; mi < 4; ++mi) {
#pragma unroll
      for (int r = 0; r < 4; ++r) {
        int row = bm + wm + mi * 16 + quad * 4 + r;
        float v = acc[mi][ni][r] + bv;
        if (EPI == 0) {
          ((u16*)Cv)[(size_t)row * N + col] = f2bf(tanhf(v));
        } else if (EPI == 1) {
          ((float*)Cv)[(size_t)row * N + col] = v;
        } else {
          ((u16*)Cv)[(size_t)row * N + col] = f2bf(v);
        }
      }
    }
  }
}

// ---------- z = mu + exp(0.5 lv) * eps ; accumulate -KL ----------
// muzlv: [B][128] f32 (0..63 mu, 64..127 lv); eps: [B][64] f32; z: [B][64] bf16
__global__ __launch_bounds__(256) void zkl_kernel(
    const float* __restrict__ muzlv, const float* __restrict__ eps,
    u16* __restrict__ z, float* __restrict__ acc) {
  float c = 0.f;
  size_t base = (size_t)blockIdx.x * 4096 + threadIdx.x;
#pragma unroll 4
  for (int j = 0; j < 16; ++j) {
    size_t idx = base + (size_t)j * 256;
    int row = (int)(idx >> 6), l = (int)(idx & 63);
    float mu = muzlv[(size_t)row * 128 + l];
    float lv = muzlv[(size_t)row * 128 + 64 + l];
    z[idx] = f2bf(mu + __expf(0.5f * lv) * eps[idx]);
    c += 1.0f + lv - mu * mu - __expf(lv);   // -kl contribution * 2
  }
  c *= 0.5f;
  for (int off = 32; off > 0; off >>= 1) c += __shfl_xor(c, off, 64);
  __shared__ float s[4];
  if ((threadIdx.x & 63) == 0) s[threadIdx.x >> 6] = c;
  __syncthreads();
  if (threadIdx.x == 0) atomicAdd(acc, s[0] + s[1] + s[2] + s[3]);
}

// ---------- softmax + diag-Gaussian log-likelihood ----------
// loglv: [B][1024] bf16 (0..511 logits, 512..1023 lv_x); x: [B][512] f32
__global__ __launch_bounds__(256) void lik_kernel(
    const u16* __restrict__ loglv, const float* __restrict__ x,
    float* __restrict__ acc) {
  const int wave = threadIdx.x >> 6, lane = threadIdx.x & 63;
  float wacc = 0.f;
  for (int rr = 0; rr < 8; ++rr) {
    int row = blockIdx.x * 32 + wave * 8 + rr;
    const u16* Lr = loglv + (size_t)row * 1024;
    short8 lg8 = ((const short8*)Lr)[lane];
    float lg[8];
#pragma unroll
    for (int j = 0; j < 8; ++j) lg[j] = bf2f((u16)lg8[j]);
    float mx = lg[0];
#pragma unroll
    for (int j = 1; j < 8; ++j) mx = fmaxf(mx, lg[j]);
    for (int off = 32; off > 0; off >>= 1) mx = fmaxf(mx, __shfl_xor(mx, off, 64));
    float e[8], s = 0.f;
#pragma unroll
    for (int j = 0; j < 8; ++j) { e[j] = __expf(lg[j] - mx); s += e[j]; }
    for (int off = 32; off > 0; off >>= 1) s += __shfl_xor(s, off, 64);
    float inv_s = 1.0f / s;
    short8 lv8 = ((const short8*)Lr)[64 + lane];
    const float* xr = x + (size_t)row * 512 + lane * 8;
    float4 x0 = *(const float4*)xr, x1 = *(const float4*)(xr + 4);
    float xs[8] = {x0.x, x0.y, x0.z, x0.w, x1.x, x1.y, x1.z, x1.w};
    float T = 0.f;
#pragma unroll
    for (int j = 0; j < 8; ++j) {
      float lv = bf2f((u16)lv8[j]);
      float d = xs[j] - e[j] * inv_s;
      T += lv + d * d * __expf(-lv) + LOG2PI_F;
    }
    for (int off = 32; off > 0; off >>= 1) T += __shfl_xor(T, off, 64);
    if (lane == 0) wacc += -0.5f * T;
  }
  __shared__ float s4[4];
  if (lane == 0) s4[wave] = wacc;
  __syncthreads();
  if (threadIdx.x == 0) atomicAdd(acc, s4[0] + s4[1] + s4[2] + s4[3]);
}

__global__ void fin_kernel(const float* __restrict__ acc, float* __restrict__ out) {
  out[0] = acc[0] * (1.0f / 65536.0f);
}

// ---------- launch ----------
extern "C" void kernel_launch(void* const* d_in, const int* in_sizes, int n_in,
                              void* d_out, int out_size, void* d_ws, size_t ws_size,
                              hipStream_t stream) {
  const int B = 65536, D = 512, H = 1024, L = 64;
  const float* x       = (const float*)d_in[0];
  const float* eps     = (const float*)d_in[1];
  const float* W_enc_h = (const float*)d_in[2];
  const float* b_enc_h = (const float*)d_in[3];
  const float* W_enc_mu= (const float*)d_in[4];
  const float* b_enc_mu= (const float*)d_in[5];
  const float* W_enc_lv= (const float*)d_in[6];
  const float* b_enc_lv= (const float*)d_in[7];
  const float* W_dec_h = (const float*)d_in[8];
  const float* b_dec_h = (const float*)d_in[9];
  const float* W_dec_mu= (const float*)d_in[10];
  const float* b_dec_mu= (const float*)d_in[11];
  const float* W_dec_lv= (const float*)d_in[12];
  const float* b_dec_lv= (const float*)d_in[13];

  char* ws = (char*)d_ws;
  // weights/bias/acc block (first 4MB)
  u16*  Wt_eh  = (u16*)(ws + 0);            // [1024][512]
  u16*  Wt_z   = (u16*)(ws + 1048576);      // [128][1024]
  u16*  Wt_dh  = (u16*)(ws + 1310720);      // [1024][64]
  u16*  Wt_dx  = (u16*)(ws + 1441792);      // [1024][1024]
  float* bh    = (float*)(ws + 3538944);    // [1024]
  float* bz    = (float*)(ws + 3543040);    // [128]
  float* bdh   = (float*)(ws + 3547136);    // [1024]
  float* bdx   = (float*)(ws + 3551232);    // [1024]
  float* acc   = (float*)(ws + 3555328);    // [1]
  // big regions
  u16*  hbuf   = (u16*)(ws + 4194304);      // [B][1024] bf16: h then hd (128MB)
  u16*  xb     = (u16*)(ws + 138412032);    // [B][512] bf16 (64MB, dies after GEMM1)
  u16*  loglv  = (u16*)(ws + 138412032);    // [B][1024] bf16 (128MB, written by GEMM56)
  float* muzlv = (float*)(ws + 205520896);  // [B][128] f32 (32MB, dies after zkl)
  u16*  zbuf   = (u16*)(ws + 239075328);    // [B][64] bf16 (8MB, dies after GEMM4)

  hipMemsetAsync(acc, 0, 256, stream);

  // ---- packing ----
  pack_xb<<<(B * D / 4 + 255) / 256, 256, 0, stream>>>(x, xb, B * D / 4);
  pack_wt<<<(D * H + 255) / 256, 256, 0, stream>>>(W_enc_h, Wt_eh, D, H);
  pack_wt2<<<(H * 2 * L + 255) / 256, 256, 0, stream>>>(W_enc_mu, W_enc_lv, Wt_z, H, L, L);
  pack_wt<<<(L * H + 255) / 256, 256, 0, stream>>>(W_dec_h, Wt_dh, L, H);
  pack_wt2<<<(H * 2 * D + 255) / 256, 256, 0, stream>>>(W_dec_mu, W_dec_lv, Wt_dx, H, D, D);
  catf<<<(H + 255) / 256, 256, 0, stream>>>(b_enc_h, b_enc_h, bh, H, 0);
  catf<<<(2 * L + 255) / 256, 256, 0, stream>>>(b_enc_mu, b_enc_lv, bz, L, L);
  catf<<<(H + 255) / 256, 256, 0, stream>>>(b_dec_h, b_dec_h, bdh, H, 0);
  catf<<<(2 * D + 255) / 256, 256, 0, stream>>>(b_dec_mu, b_dec_lv, bdx, D, D);

  // ---- encoder: h = tanh(x @ W_enc_h + b) ----
  gemm_bt<0><<<dim3(B / 128, H / 128), 256, 0, stream>>>(xb, Wt_eh, bh, hbuf, B, H, D);
  // ---- mu_z | lv_z = h @ [W_enc_mu|W_enc_lv] + b ----
  gemm_bt<1><<<dim3(B / 128, 1), 256, 0, stream>>>(hbuf, Wt_z, bz, muzlv, B, 128, H);
  // ---- z + KL ----
  zkl_kernel<<<B * 64 / 4096, 256, 0, stream>>>(muzlv, eps, zbuf, acc);
  // ---- decoder hidden: hd = tanh(z @ W_dec_h + b) (overwrites hbuf) ----
  gemm_bt<0><<<dim3(B / 128, H / 128), 256, 0, stream>>>(zbuf, Wt_dh, bdh, hbuf, B, H, L);
  // ---- logits | lv_x = hd @ [W_dec_mu|W_dec_lv] + b ----
  gemm_bt<2><<<dim3(B / 128, 1024 / 128), 256, 0, stream>>>(hbuf, Wt_dx, bdx, loglv, B, 1024, H);
  // ---- softmax + log-likelihood ----
  lik_kernel<<<B / 32, 256, 0, stream>>>(loglv, x, acc);
  // ---- finalize mean ----
  fin_kernel<<<1, 1, 0, stream>>>(acc, (float*)d_out);
}

// Round 2
// 747.670 us; speedup vs baseline: 1.0342x; 1.0342x over previous
//
#include <hip/hip_runtime.h>

typedef unsigned short u16;
typedef unsigned int u32;
typedef __attribute__((ext_vector_type(8))) short short8;
typedef __attribute__((ext_vector_type(4))) float floatx4;

#define LOG2PI_F 1.8378770664093453f

// ---------- helpers ----------
__device__ __forceinline__ u16 f2bf(float f) {
  union { float f; u32 i; } c; c.f = f;
  u32 i = c.i;
  u32 r = (i + 0x7fffu + ((i >> 16) & 1u)) >> 16;   // RNE (inputs finite)
  return (u16)r;
}
__device__ __forceinline__ float bf2f(u16 u) {
  union { u32 i; float f; } c; c.i = ((u32)u) << 16; return c.f;
}
__device__ __forceinline__ void llds16(const void* g, void* l) {
  __builtin_amdgcn_global_load_lds(
      (const __attribute__((address_space(1))) u32*)g,
      (__attribute__((address_space(3))) u32*)l, 16, 0, 0);
}
#define SWZ(m, kc) ((kc) ^ (((m) >> 1) & 3))

// ---------- packing kernels ----------
__global__ void pack_xb(const float* __restrict__ in, u16* __restrict__ out, int n4) {
  int i = blockIdx.x * 256 + threadIdx.x;
  if (i >= n4) return;
  const float4 v = ((const float4*)in)[i];
  ushort4 o;
  o.x = f2bf(v.x); o.y = f2bf(v.y); o.z = f2bf(v.z); o.w = f2bf(v.w);
  ((ushort4*)out)[i] = o;
}

// W [K][N] fp32 -> Wt [N][K] bf16
__global__ void pack_wt(const float* __restrict__ W, u16* __restrict__ Wt, int K, int N) {
  int idx = blockIdx.x * 256 + threadIdx.x;
  if (idx >= K * N) return;
  int k = idx / N, n = idx - k * N;
  Wt[(size_t)n * K + k] = f2bf(W[idx]);
}

// W1 [K][N1], W2 [K][N2] fp32 -> Wt [(N1+N2)][K] bf16
__global__ void pack_wt2(const float* __restrict__ W1, const float* __restrict__ W2,
                         u16* __restrict__ Wt, int K, int N1, int N2) {
  int idx = blockIdx.x * 256 + threadIdx.x;
  if (idx >= (N1 + N2) * K) return;
  int n = idx / K, k = idx - n * K;
  float v = (n < N1) ? W1[(size_t)k * N1 + n] : W2[(size_t)k * N2 + (n - N1)];
  Wt[idx] = f2bf(v);
}

__global__ void catf(const float* __restrict__ a, const float* __restrict__ b,
                     float* __restrict__ o, int n1, int n2) {
  int i = blockIdx.x * 256 + threadIdx.x;
  if (i < n1) o[i] = a[i];
  else if (i < n1 + n2) o[i] = b[i - n1];
}

// ---------- MFMA GEMM: C = epi(A @ Bt^T + bias) ----------
// A: [M][K] bf16, Bt: [N][K] bf16, bias: [N] f32
// Grid: (N/128, M/128) — N-tile fastest so consecutive blocks share the A-strip
// EPI 0: tanh -> bf16 ; 2: plain -> bf16
template <int EPI>
__global__ __launch_bounds__(256) void gemm_bt(
    const u16* __restrict__ A, const u16* __restrict__ Bt,
    const float* __restrict__ bias, void* __restrict__ Cv,
    int M, int N, int K) {
  __shared__ u16 As[128 * 32];
  __shared__ u16 Bs[128 * 32];
  const int t = threadIdx.x;
  const int wave = t >> 6, lane = t & 63;
  const int quad = lane >> 4, l16 = lane & 15;
  const int bm = blockIdx.y * 128, bn = blockIdx.x * 128;
  const int wm = (wave >> 1) * 64, wn = (wave & 1) * 64;

  floatx4 acc[4][4];
#pragma unroll
  for (int i = 0; i < 4; ++i)
#pragma unroll
    for (int j = 0; j < 4; ++j) acc[i][j] = (floatx4){0.f, 0.f, 0.f, 0.f};

  for (int kt = 0; kt < K; kt += 32) {
#pragma unroll
    for (int i = 0; i < 2; ++i) {
      int c = i * 256 + t;
      int r = c >> 2, kcS = c & 3;
      int kc = SWZ(r, kcS);
      llds16(A + (size_t)(bm + r) * K + kt + kc * 8, &As[c * 8]);
      llds16(Bt + (size_t)(bn + r) * K + kt + kc * 8, &Bs[c * 8]);
    }
    __builtin_amdgcn_s_waitcnt(0);
    __syncthreads();

    const short8* As8 = (const short8*)As;
    const short8* Bs8 = (const short8*)Bs;
    short8 af[4], bf[4];
#pragma unroll
    for (int mi = 0; mi < 4; ++mi) {
      int m = wm + mi * 16 + l16;
      af[mi] = As8[m * 4 + SWZ(m, quad)];
    }
#pragma unroll
    for (int ni = 0; ni < 4; ++ni) {
      int n = wn + ni * 16 + l16;
      bf[ni] = Bs8[n * 4 + SWZ(n, quad)];
    }
#pragma unroll
    for (int mi = 0; mi < 4; ++mi)
#pragma unroll
      for (int ni = 0; ni < 4; ++ni)
        acc[mi][ni] = __builtin_amdgcn_mfma_f32_16x16x32_bf16(
            af[mi], bf[ni], acc[mi][ni], 0, 0, 0);
    __syncthreads();
  }

  // epilogue: D[row=quad*4+r][col=lane&15]  (m89/m91-verified layout)
#pragma unroll
  for (int ni = 0; ni < 4; ++ni) {
    int col = bn + wn + ni * 16 + l16;
    float bv = bias[col];
#pragma unroll
    for (int mi = 0; mi < 4; ++mi) {
#pragma unroll
      for (int r = 0; r < 4; ++r) {
        int row = bm + wm + mi * 16 + quad * 4 + r;
        float v = acc[mi][ni][r] + bv;
        if (EPI == 0) {
          ((u16*)Cv)[(size_t)row * N + col] = f2bf(tanhf(v));
        } else {
          ((u16*)Cv)[(size_t)row * N + col] = f2bf(v);
        }
      }
    }
  }
}

// ---------- fused GEMM23 + reparameterise + KL ----------
// A: [M][1024] bf16 (h), Bt: [128][1024] bf16 ([W_enc_mu|W_enc_lv]^T),
// bias: [128] f32. Cols 0..63 = mu_z, 64..127 = lv_z.
// Writes z [M][64] bf16; atomicAdd Σ(-kl) into acc.
// Grid: (1, M/128).
__global__ __launch_bounds__(256) void gemm_z(
    const u16* __restrict__ A, const u16* __restrict__ Bt,
    const float* __restrict__ bias, const float* __restrict__ eps,
    u16* __restrict__ z, float* __restrict__ accp, int M, int K) {
  __shared__ u16 As[128 * 32];
  __shared__ u16 Bs[128 * 32];
  __shared__ float sexp[128 * 64];   // exp(0.5*lv) staging [row][col]
  const int t = threadIdx.x;
  const int wave = t >> 6, lane = t & 63;
  const int quad = lane >> 4, l16 = lane & 15;
  const int bm = blockIdx.y * 128;
  const int wm = (wave >> 1) * 64, wn = (wave & 1) * 64;

  floatx4 acc[4][4];
#pragma unroll
  for (int i = 0; i < 4; ++i)
#pragma unroll
    for (int j = 0; j < 4; ++j) acc[i][j] = (floatx4){0.f, 0.f, 0.f, 0.f};

  for (int kt = 0; kt < K; kt += 32) {
#pragma unroll
    for (int i = 0; i < 2; ++i) {
      int c = i * 256 + t;
      int r = c >> 2, kcS = c & 3;
      int kc = SWZ(r, kcS);
      llds16(A + (size_t)(bm + r) * K + kt + kc * 8, &As[c * 8]);
      llds16(Bt + (size_t)r * K + kt + kc * 8, &Bs[c * 8]);
    }
    __builtin_amdgcn_s_waitcnt(0);
    __syncthreads();

    const short8* As8 = (const short8*)As;
    const short8* Bs8 = (const short8*)Bs;
    short8 af[4], bf[4];
#pragma unroll
    for (int mi = 0; mi < 4; ++mi) {
      int m = wm + mi * 16 + l16;
      af[mi] = As8[m * 4 + SWZ(m, quad)];
    }
#pragma unroll
    for (int ni = 0; ni < 4; ++ni) {
      int n = wn + ni * 16 + l16;
      bf[ni] = Bs8[n * 4 + SWZ(n, quad)];
    }
#pragma unroll
    for (int mi = 0; mi < 4; ++mi)
#pragma unroll
      for (int ni = 0; ni < 4; ++ni)
        acc[mi][ni] = __builtin_amdgcn_mfma_f32_16x16x32_bf16(
            af[mi], bf[ni], acc[mi][ni], 0, 0, 0);
    __syncthreads();
  }

  const bool is_lv = (wave & 1);
  float kl = 0.f;
#pragma unroll
  for (int ni = 0; ni < 4; ++ni) {
    int col = wn + ni * 16 + l16;            // 0..127
    float bv = bias[col];
#pragma unroll
    for (int mi = 0; mi < 4; ++mi) {
#pragma unroll
      for (int r = 0; r < 4; ++r) {
        int row = wm + mi * 16 + quad * 4 + r;   // 0..127 local
        float v = acc[mi][ni][r] + bv;
        if (is_lv) {
          kl += 1.0f + v - __expf(v);
          sexp[row * 64 + (col - 64)] = __expf(0.5f * v);
        } else {
          kl -= v * v;
        }
      }
    }
  }
  __syncthreads();
  if (!is_lv) {
#pragma unroll
    for (int ni = 0; ni < 4; ++ni) {
      int col = wn + ni * 16 + l16;          // 0..63
      float bv = bias[col];
#pragma unroll
      for (int mi = 0; mi < 4; ++mi) {
#pragma unroll
        for (int r = 0; r < 4; ++r) {
          int row = wm + mi * 16 + quad * 4 + r;
          float mu = acc[mi][ni][r] + bv;
          size_t grow = (size_t)(bm + row);
          float ep = eps[grow * 64 + col];
          z[grow * 64 + col] = f2bf(mu + sexp[row * 64 + col] * ep);
        }
      }
    }
  }
  kl *= 0.5f;
  for (int off = 32; off > 0; off >>= 1) kl += __shfl_xor(kl, off, 64);
  __shared__ float s4[4];
  if (lane == 0) s4[wave] = kl;
  __syncthreads();
  if (t == 0) atomicAdd(accp, s4[0] + s4[1] + s4[2] + s4[3]);
}

// ---------- softmax + diag-Gaussian log-likelihood ----------
// loglv: [B][1024] bf16 (0..511 logits, 512..1023 lv_x); x: [B][512] f32
__global__ __launch_bounds__(256) void lik_kernel(
    const u16* __restrict__ loglv, const float* __restrict__ x,
    float* __restrict__ acc) {
  const int wave = threadIdx.x >> 6, lane = threadIdx.x & 63;
  float wacc = 0.f;
  for (int rr = 0; rr < 8; ++rr) {
    int row = blockIdx.x * 32 + wave * 8 + rr;
    const u16* Lr = loglv + (size_t)row * 1024;
    short8 lg8 = ((const short8*)Lr)[lane];
    float lg[8];
#pragma unroll
    for (int j = 0; j < 8; ++j) lg[j] = bf2f((u16)lg8[j]);
    float mx = lg[0];
#pragma unroll
    for (int j = 1; j < 8; ++j) mx = fmaxf(mx, lg[j]);
    for (int off = 32; off > 0; off >>= 1) mx = fmaxf(mx, __shfl_xor(mx, off, 64));
    float e[8], s = 0.f;
#pragma unroll
    for (int j = 0; j < 8; ++j) { e[j] = __expf(lg[j] - mx); s += e[j]; }
    for (int off = 32; off > 0; off >>= 1) s += __shfl_xor(s, off, 64);
    float inv_s = 1.0f / s;
    short8 lv8 = ((const short8*)Lr)[64 + lane];
    const float* xr = x + (size_t)row * 512 + lane * 8;
    float4 x0 = *(const float4*)xr, x1 = *(const float4*)(xr + 4);
    float xs[8] = {x0.x, x0.y, x0.z, x0.w, x1.x, x1.y, x1.z, x1.w};
    float T = 0.f;
#pragma unroll
    for (int j = 0; j < 8; ++j) {
      float lv = bf2f((u16)lv8[j]);
      float d = xs[j] - e[j] * inv_s;
      T += lv + d * d * __expf(-lv) + LOG2PI_F;
    }
    for (int off = 32; off > 0; off >>= 1) T += __shfl_xor(T, off, 64);
    if (lane == 0) wacc += -0.5f * T;
  }
  __shared__ float s4[4];
  if (lane == 0) s4[wave] = wacc;
  __syncthreads();
  if (threadIdx.x == 0) atomicAdd(acc, s4[0] + s4[1] + s4[2] + s4[3]);
}

__global__ void fin_kernel(const float* __restrict__ acc, float* __restrict__ out) {
  out[0] = acc[0] * (1.0f / 65536.0f);
}

// ---------- launch ----------
extern "C" void kernel_launch(void* const* d_in, const int* in_sizes, int n_in,
                              void* d_out, int out_size, void* d_ws, size_t ws_size,
                              hipStream_t stream) {
  const int B = 65536, D = 512, H = 1024, L = 64;
  const float* x       = (const float*)d_in[0];
  const float* eps     = (const float*)d_in[1];
  const float* W_enc_h = (const float*)d_in[2];
  const float* b_enc_h = (const float*)d_in[3];
  const float* W_enc_mu= (const float*)d_in[4];
  const float* b_enc_mu= (const float*)d_in[5];
  const float* W_enc_lv= (const float*)d_in[6];
  const float* b_enc_lv= (const float*)d_in[7];
  const float* W_dec_h = (const float*)d_in[8];
  const float* b_dec_h = (const float*)d_in[9];
  const float* W_dec_mu= (const float*)d_in[10];
  const float* b_dec_mu= (const float*)d_in[11];
  const float* W_dec_lv= (const float*)d_in[12];
  const float* b_dec_lv= (const float*)d_in[13];

  char* ws = (char*)d_ws;
  // weights/bias/acc block (first 4MB)
  u16*  Wt_eh  = (u16*)(ws + 0);            // [1024][512]
  u16*  Wt_z   = (u16*)(ws + 1048576);      // [128][1024]
  u16*  Wt_dh  = (u16*)(ws + 1310720);      // [1024][64]
  u16*  Wt_dx  = (u16*)(ws + 1441792);      // [1024][1024]
  float* bh    = (float*)(ws + 3538944);    // [1024]
  float* bz    = (float*)(ws + 3543040);    // [128]
  float* bdh   = (float*)(ws + 3547136);    // [1024]
  float* bdx   = (float*)(ws + 3551232);    // [1024]
  float* acc   = (float*)(ws + 3555328);    // [1]
  // big regions (peak footprint 272.6 MB, same as round 1)
  u16*  hbuf   = (u16*)(ws + 4194304);      // [B][1024] bf16: h then hd (128MB)
  u16*  xb     = (u16*)(ws + 138412032);    // [B][512] bf16 (dead after GEMM1)
  u16*  zbuf   = (u16*)(ws + 205520896);    // [B][64] bf16 (dead after GEMM4)
  u16*  loglv  = (u16*)(ws + 138412032);    // [B][1024] bf16 (overwrites xb+zbuf after GEMM4)

  hipMemsetAsync(acc, 0, 256, stream);

  // ---- packing ----
  pack_xb<<<(B * D / 4 + 255) / 256, 256, 0, stream>>>(x, xb, B * D / 4);
  pack_wt<<<(D * H + 255) / 256, 256, 0, stream>>>(W_enc_h, Wt_eh, D, H);
  pack_wt2<<<(H * 2 * L + 255) / 256, 256, 0, stream>>>(W_enc_mu, W_enc_lv, Wt_z, H, L, L);
  pack_wt<<<(L * H + 255) / 256, 256, 0, stream>>>(W_dec_h, Wt_dh, L, H);
  pack_wt2<<<(H * 2 * D + 255) / 256, 256, 0, stream>>>(W_dec_mu, W_dec_lv, Wt_dx, H, D, D);
  catf<<<(H + 255) / 256, 256, 0, stream>>>(b_enc_h, b_enc_h, bh, H, 0);
  catf<<<(2 * L + 255) / 256, 256, 0, stream>>>(b_enc_mu, b_enc_lv, bz, L, L);
  catf<<<(H + 255) / 256, 256, 0, stream>>>(b_dec_h, b_dec_h, bdh, H, 0);
  catf<<<(2 * D + 255) / 256, 256, 0, stream>>>(b_dec_mu, b_dec_lv, bdx, D, D);

  // ---- encoder: h = tanh(x @ W_enc_h + b) ----
  gemm_bt<0><<<dim3(H / 128, B / 128), 256, 0, stream>>>(xb, Wt_eh, bh, hbuf, B, H, D);
  // ---- fused: mu|lv = h @ Wt_z + b ; z = mu + exp(.5 lv) eps ; KL ----
  gemm_z<<<dim3(1, B / 128), 256, 0, stream>>>(hbuf, Wt_z, bz, eps, zbuf, acc, B, H);
  // ---- decoder hidden: hd = tanh(z @ W_dec_h + b) (overwrites hbuf) ----
  gemm_bt<0><<<dim3(H / 128, B / 128), 256, 0, stream>>>(zbuf, Wt_dh, bdh, hbuf, B, H, L);
  // ---- logits | lv_x = hd @ [W_dec_mu|W_dec_lv] + b ----
  gemm_bt<2><<<dim3(1024 / 128, B / 128), 256, 0, stream>>>(hbuf, Wt_dx, bdx, loglv, B, 1024, H);
  // ---- softmax + log-likelihood ----
  lik_kernel<<<B / 32, 256, 0, stream>>>(loglv, x, acc);
  // ---- finalize mean ----
  fin_kernel<<<1, 1, 0, stream>>>(acc, (float*)d_out);
}

// Round 3
// 628.305 us; speedup vs baseline: 1.2306x; 1.1900x over previous
//
#include <hip/hip_runtime.h>

typedef unsigned char u8;
typedef unsigned short u16;
typedef unsigned int u32;
typedef long i64;
typedef __attribute__((ext_vector_type(4))) float floatx4;

#define LOG2PI_F 1.8378770664093453f

// ---------- helpers ----------
__device__ __forceinline__ u16 f2bf(float f) {
  union { float f; u32 i; } c; c.f = f;
  u32 i = c.i;
  u32 r = (i + 0x7fffu + ((i >> 16) & 1u)) >> 16;   // RNE (inputs finite)
  return (u16)r;
}
__device__ __forceinline__ float bf2f(u16 u) {
  union { u32 i; float f; } c; c.i = ((u32)u) << 16; return c.f;
}
__device__ __forceinline__ u8 f2fp8(float f) {
  int p = __builtin_amdgcn_cvt_pk_fp8_f32(f, f, 0, false);
  return (u8)(p & 0xff);
}
__device__ __forceinline__ u32 pk4fp8(float a, float b, float c, float d) {
  int lo = __builtin_amdgcn_cvt_pk_fp8_f32(a, b, 0, false);
  int v  = __builtin_amdgcn_cvt_pk_fp8_f32(c, d, lo, true);
  return (u32)v;
}
__device__ __forceinline__ void llds16(const void* g, void* l) {
  __builtin_amdgcn_global_load_lds(
      (const __attribute__((address_space(1))) u32*)g,
      (__attribute__((address_space(3))) u32*)l, 16, 0, 0);
}

// Scales (powers of 2; keep e4m3 out of subnormals):
//   x*16, weights*256, tanh-activations*64, z*16. Inverses folded into epilogues.
#define INV_4096  2.44140625e-4f
#define INV_16384 6.103515625e-5f

// ---------- packing kernels ----------
__global__ void pack_xb(const float* __restrict__ in, u32* __restrict__ out, int n4) {
  int i = blockIdx.x * 256 + threadIdx.x;
  if (i >= n4) return;
  const float4 v = ((const float4*)in)[i];
  out[i] = pk4fp8(v.x * 16.f, v.y * 16.f, v.z * 16.f, v.w * 16.f);
}

// W [K][N] fp32 -> Wt [N][K] fp8 (*256)
__global__ void pack_wt(const float* __restrict__ W, u8* __restrict__ Wt, int K, int N) {
  int idx = blockIdx.x * 256 + threadIdx.x;
  if (idx >= K * N) return;
  int k = idx / N, n = idx - k * N;
  Wt[(size_t)n * K + k] = f2fp8(W[idx] * 256.f);
}

// W1 [K][N1], W2 [K][N2] fp32 -> Wt [(N1+N2)][K] fp8 (*256)
__global__ void pack_wt2(const float* __restrict__ W1, const float* __restrict__ W2,
                         u8* __restrict__ Wt, int K, int N1, int N2) {
  int idx = blockIdx.x * 256 + threadIdx.x;
  if (idx >= (N1 + N2) * K) return;
  int n = idx / K, k = idx - n * K;
  float v = (n < N1) ? W1[(size_t)k * N1 + n] : W2[(size_t)k * N2 + (n - N1)];
  Wt[idx] = f2fp8(v * 256.f);
}

__global__ void catf(const float* __restrict__ a, const float* __restrict__ b,
                     float* __restrict__ o, int n1, int n2) {
  int i = blockIdx.x * 256 + threadIdx.x;
  if (i < n1) o[i] = a[i];
  else if (i < n1 + n2) o[i] = b[i - n1];
}

// ---------- fp8 MFMA GEMM: C = epi(A @ Bt^T * inv + bias) ----------
// A: [M][K] fp8, Bt: [N][K] fp8, bias: [N] f32. BK=64, 2-bit XOR chunk swizzle.
// EPI 0: tanh -> fp8*outs ; 2: plain -> bf16
template <int EPI>
__global__ __launch_bounds__(256) void gemm_bt(
    const u8* __restrict__ A, const u8* __restrict__ Bt,
    const float* __restrict__ bias, void* __restrict__ Cv,
    float inv, float outs, int M, int N, int K) {
  __shared__ __align__(16) u8 As[128 * 64];
  __shared__ __align__(16) u8 Bs[128 * 64];
  const int t = threadIdx.x;
  const int wave = t >> 6, lane = t & 63;
  const int quad = lane >> 4, l16 = lane & 15;
  const int bm = blockIdx.y * 128, bn = blockIdx.x * 128;
  const int wm = (wave >> 1) * 64, wn = (wave & 1) * 64;
  const int sw = (l16 >> 2) & 3;

  floatx4 acc[4][4];
#pragma unroll
  for (int i = 0; i < 4; ++i)
#pragma unroll
    for (int j = 0; j < 4; ++j) acc[i][j] = (floatx4){0.f, 0.f, 0.f, 0.f};

  for (int kt = 0; kt < K; kt += 64) {
#pragma unroll
    for (int i = 0; i < 2; ++i) {
      int c = i * 256 + t;
      int r = c >> 2, kcS = c & 3;
      int kc = kcS ^ ((r >> 2) & 3);
      llds16(A + (size_t)(bm + r) * K + kt + kc * 16, &As[c * 16]);
      llds16(Bt + (size_t)(bn + r) * K + kt + kc * 16, &Bs[c * 16]);
    }
    __builtin_amdgcn_s_waitcnt(0);
    __syncthreads();
#pragma unroll
    for (int h = 0; h < 2; ++h) {
      i64 af[4], bfr[4];
#pragma unroll
      for (int mi = 0; mi < 4; ++mi) {
        int m = wm + mi * 16 + l16;
        af[mi] = *(const i64*)&As[(4 * m + ((2 * h + (quad >> 1)) ^ sw)) * 16 + (quad & 1) * 8];
      }
#pragma unroll
      for (int ni = 0; ni < 4; ++ni) {
        int n = wn + ni * 16 + l16;
        bfr[ni] = *(const i64*)&Bs[(4 * n + ((2 * h + (quad >> 1)) ^ sw)) * 16 + (quad & 1) * 8];
      }
#pragma unroll
      for (int mi = 0; mi < 4; ++mi)
#pragma unroll
        for (int ni = 0; ni < 4; ++ni)
          acc[mi][ni] = __builtin_amdgcn_mfma_f32_16x16x32_fp8_fp8(
              af[mi], bfr[ni], acc[mi][ni], 0, 0, 0);
    }
    __syncthreads();
  }

  // epilogue: D[row=quad*4+r][col=lane&15]  (layout dtype-independent, m121-m128)
#pragma unroll
  for (int ni = 0; ni < 4; ++ni) {
    int col = bn + wn + ni * 16 + l16;
    float bv = bias[col];
#pragma unroll
    for (int mi = 0; mi < 4; ++mi) {
#pragma unroll
      for (int r = 0; r < 4; ++r) {
        int row = bm + wm + mi * 16 + quad * 4 + r;
        float v = acc[mi][ni][r] * inv + bv;
        if (EPI == 0) {
          ((u8*)Cv)[(size_t)row * N + col] = f2fp8(tanhf(v) * outs);
        } else {
          ((u16*)Cv)[(size_t)row * N + col] = f2bf(v);
        }
      }
    }
  }
}

// ---------- fused GEMM23 + reparameterise + KL (fp8) ----------
// A: [M][K] fp8 (h*64), Bt: [128][K] fp8 ([W_enc_mu|W_enc_lv]^T*256), bias [128].
// Cols 0..63 = mu_z, 64..127 = lv_z. Writes z [M][64] fp8 (*16); atomicAdd Σ(-kl).
__global__ __launch_bounds__(256) void gemm_z(
    const u8* __restrict__ A, const u8* __restrict__ Bt,
    const float* __restrict__ bias, const float* __restrict__ eps,
    u8* __restrict__ z, float* __restrict__ accp, int M, int K) {
  __shared__ __align__(16) u8 As[128 * 64];
  __shared__ __align__(16) u8 Bs[128 * 64];
  __shared__ float sexp[128 * 64];   // exp(0.5*lv) staging [row][col]
  const int t = threadIdx.x;
  const int wave = t >> 6, lane = t & 63;
  const int quad = lane >> 4, l16 = lane & 15;
  const int bm = blockIdx.y * 128;
  const int wm = (wave >> 1) * 64, wn = (wave & 1) * 64;
  const int sw = (l16 >> 2) & 3;

  floatx4 acc[4][4];
#pragma unroll
  for (int i = 0; i < 4; ++i)
#pragma unroll
    for (int j = 0; j < 4; ++j) acc[i][j] = (floatx4){0.f, 0.f, 0.f, 0.f};

  for (int kt = 0; kt < K; kt += 64) {
#pragma unroll
    for (int i = 0; i < 2; ++i) {
      int c = i * 256 + t;
      int r = c >> 2, kcS = c & 3;
      int kc = kcS ^ ((r >> 2) & 3);
      llds16(A + (size_t)(bm + r) * K + kt + kc * 16, &As[c * 16]);
      llds16(Bt + (size_t)r * K + kt + kc * 16, &Bs[c * 16]);
    }
    __builtin_amdgcn_s_waitcnt(0);
    __syncthreads();
#pragma unroll
    for (int h = 0; h < 2; ++h) {
      i64 af[4], bfr[4];
#pragma unroll
      for (int mi = 0; mi < 4; ++mi) {
        int m = wm + mi * 16 + l16;
        af[mi] = *(const i64*)&As[(4 * m + ((2 * h + (quad >> 1)) ^ sw)) * 16 + (quad & 1) * 8];
      }
#pragma unroll
      for (int ni = 0; ni < 4; ++ni) {
        int n = wn + ni * 16 + l16;
        bfr[ni] = *(const i64*)&Bs[(4 * n + ((2 * h + (quad >> 1)) ^ sw)) * 16 + (quad & 1) * 8];
      }
#pragma unroll
      for (int mi = 0; mi < 4; ++mi)
#pragma unroll
        for (int ni = 0; ni < 4; ++ni)
          acc[mi][ni] = __builtin_amdgcn_mfma_f32_16x16x32_fp8_fp8(
              af[mi], bfr[ni], acc[mi][ni], 0, 0, 0);
    }
    __syncthreads();
  }

  const bool is_lv = (wave & 1);
  float kl = 0.f;
#pragma unroll
  for (int ni = 0; ni < 4; ++ni) {
    int col = wn + ni * 16 + l16;            // 0..127
    float bv = bias[col];
#pragma unroll
    for (int mi = 0; mi < 4; ++mi) {
#pragma unroll
      for (int r = 0; r < 4; ++r) {
        int row = wm + mi * 16 + quad * 4 + r;   // 0..127 local
        float v = acc[mi][ni][r] * INV_16384 + bv;
        if (is_lv) {
          kl += 1.0f + v - __expf(v);
          sexp[row * 64 + (col - 64)] = __expf(0.5f * v);
        } else {
          kl -= v * v;
        }
      }
    }
  }
  __syncthreads();
  if (!is_lv) {
#pragma unroll
    for (int ni = 0; ni < 4; ++ni) {
      int col = wn + ni * 16 + l16;          // 0..63
      float bv = bias[col];
#pragma unroll
      for (int mi = 0; mi < 4; ++mi) {
#pragma unroll
        for (int r = 0; r < 4; ++r) {
          int row = wm + mi * 16 + quad * 4 + r;
          float mu = acc[mi][ni][r] * INV_16384 + bv;
          size_t grow = (size_t)(bm + row);
          float ep = eps[grow * 64 + col];
          z[grow * 64 + col] = f2fp8((mu + sexp[row * 64 + col] * ep) * 16.f);
        }
      }
    }
  }
  kl *= 0.5f;
  for (int off = 32; off > 0; off >>= 1) kl += __shfl_xor(kl, off, 64);
  __shared__ float s4[4];
  if (lane == 0) s4[wave] = kl;
  __syncthreads();
  if (t == 0) atomicAdd(accp, s4[0] + s4[1] + s4[2] + s4[3]);
}

// ---------- softmax + diag-Gaussian log-likelihood ----------
// loglv: [B][1024] bf16 (0..511 logits, 512..1023 lv_x); x: [B][512] f32
__global__ __launch_bounds__(256) void lik_kernel(
    const u16* __restrict__ loglv, const float* __restrict__ x,
    float* __restrict__ acc) {
  typedef __attribute__((ext_vector_type(8))) short short8;
  const int wave = threadIdx.x >> 6, lane = threadIdx.x & 63;
  float wacc = 0.f;
  for (int rr = 0; rr < 8; ++rr) {
    int row = blockIdx.x * 32 + wave * 8 + rr;
    const u16* Lr = loglv + (size_t)row * 1024;
    short8 lg8 = ((const short8*)Lr)[lane];
    float lg[8];
#pragma unroll
    for (int j = 0; j < 8; ++j) lg[j] = bf2f((u16)lg8[j]);
    float mx = lg[0];
#pragma unroll
    for (int j = 1; j < 8; ++j) mx = fmaxf(mx, lg[j]);
    for (int off = 32; off > 0; off >>= 1) mx = fmaxf(mx, __shfl_xor(mx, off, 64));
    float e[8], s = 0.f;
#pragma unroll
    for (int j = 0; j < 8; ++j) { e[j] = __expf(lg[j] - mx); s += e[j]; }
    for (int off = 32; off > 0; off >>= 1) s += __shfl_xor(s, off, 64);
    float inv_s = 1.0f / s;
    short8 lv8 = ((const short8*)Lr)[64 + lane];
    const float* xr = x + (size_t)row * 512 + lane * 8;
    float4 x0 = *(const float4*)xr, x1 = *(const float4*)(xr + 4);
    float xs[8] = {x0.x, x0.y, x0.z, x0.w, x1.x, x1.y, x1.z, x1.w};
    float T = 0.f;
#pragma unroll
    for (int j = 0; j < 8; ++j) {
      float lv = bf2f((u16)lv8[j]);
      float d = xs[j] - e[j] * inv_s;
      T += lv + d * d * __expf(-lv) + LOG2PI_F;
    }
    for (int off = 32; off > 0; off >>= 1) T += __shfl_xor(T, off, 64);
    if (lane == 0) wacc += -0.5f * T;
  }
  __shared__ float s4[4];
  if (lane == 0) s4[wave] = wacc;
  __syncthreads();
  if (threadIdx.x == 0) atomicAdd(acc, s4[0] + s4[1] + s4[2] + s4[3]);
}

__global__ void fin_kernel(const float* __restrict__ acc, float* __restrict__ out) {
  out[0] = acc[0] * (1.0f / 65536.0f);
}

// ---------- launch ----------
extern "C" void kernel_launch(void* const* d_in, const int* in_sizes, int n_in,
                              void* d_out, int out_size, void* d_ws, size_t ws_size,
                              hipStream_t stream) {
  const int B = 65536, D = 512, H = 1024, L = 64;
  const float* x       = (const float*)d_in[0];
  const float* eps     = (const float*)d_in[1];
  const float* W_enc_h = (const float*)d_in[2];
  const float* b_enc_h = (const float*)d_in[3];
  const float* W_enc_mu= (const float*)d_in[4];
  const float* b_enc_mu= (const float*)d_in[5];
  const float* W_enc_lv= (const float*)d_in[6];
  const float* b_enc_lv= (const float*)d_in[7];
  const float* W_dec_h = (const float*)d_in[8];
  const float* b_dec_h = (const float*)d_in[9];
  const float* W_dec_mu= (const float*)d_in[10];
  const float* b_dec_mu= (const float*)d_in[11];
  const float* W_dec_lv= (const float*)d_in[12];
  const float* b_dec_lv= (const float*)d_in[13];

  char* ws = (char*)d_ws;
  // weights (fp8) / bias / acc block
  u8*   Wt_eh  = (u8*)(ws + 0);             // [1024][512]  512K
  u8*   Wt_z   = (u8*)(ws + 524288);        // [128][1024]  128K
  u8*   Wt_dh  = (u8*)(ws + 655360);        // [1024][64]    64K
  u8*   Wt_dx  = (u8*)(ws + 720896);        // [1024][1024]   1M
  float* bh    = (float*)(ws + 2097152);    // [1024]
  float* bz    = (float*)(ws + 2101248);    // [128]
  float* bdh   = (float*)(ws + 2105344);    // [1024]
  float* bdx   = (float*)(ws + 2109440);    // [1024]
  float* acc   = (float*)(ws + 2113536);    // [1]
  // big regions (peak 232 MB)
  u8*   hbuf   = (u8*)(ws + 4194304);       // [B][1024] fp8: h then hd (64MB)
  u8*   xb     = (u8*)(ws + 71303168);      // [B][512] fp8 (32MB, dead after GEMM1)
  u8*   zbuf   = (u8*)(ws + 104857600);     // [B][64] fp8 (4MB, dead after GEMM4)
  u16*  loglv  = (u16*)(ws + 109051904);    // [B][1024] bf16 (128MB)

  hipMemsetAsync(acc, 0, 256, stream);

  // ---- packing ----
  pack_xb<<<(B * D / 4 + 255) / 256, 256, 0, stream>>>(x, (u32*)xb, B * D / 4);
  pack_wt<<<(D * H + 255) / 256, 256, 0, stream>>>(W_enc_h, Wt_eh, D, H);
  pack_wt2<<<(H * 2 * L + 255) / 256, 256, 0, stream>>>(W_enc_mu, W_enc_lv, Wt_z, H, L, L);
  pack_wt<<<(L * H + 255) / 256, 256, 0, stream>>>(W_dec_h, Wt_dh, L, H);
  pack_wt2<<<(H * 2 * D + 255) / 256, 256, 0, stream>>>(W_dec_mu, W_dec_lv, Wt_dx, H, D, D);
  catf<<<(H + 255) / 256, 256, 0, stream>>>(b_enc_h, b_enc_h, bh, H, 0);
  catf<<<(2 * L + 255) / 256, 256, 0, stream>>>(b_enc_mu, b_enc_lv, bz, L, L);
  catf<<<(H + 255) / 256, 256, 0, stream>>>(b_dec_h, b_dec_h, bdh, H, 0);
  catf<<<(2 * D + 255) / 256, 256, 0, stream>>>(b_dec_mu, b_dec_lv, bdx, D, D);

  // ---- encoder: h = tanh(x @ W_enc_h + b), h stored fp8*64 ----
  gemm_bt<0><<<dim3(H / 128, B / 128), 256, 0, stream>>>(
      xb, Wt_eh, bh, hbuf, INV_4096, 64.f, B, H, D);
  // ---- fused: mu|lv = h @ Wt_z + b ; z = mu + exp(.5 lv) eps (fp8*16) ; KL ----
  gemm_z<<<dim3(1, B / 128), 256, 0, stream>>>(hbuf, Wt_z, bz, eps, zbuf, acc, B, H);
  // ---- decoder hidden: hd = tanh(z @ W_dec_h + b), fp8*64 (overwrites hbuf) ----
  gemm_bt<0><<<dim3(H / 128, B / 128), 256, 0, stream>>>(
      zbuf, Wt_dh, bdh, hbuf, INV_4096, 64.f, B, H, L);
  // ---- logits | lv_x = hd @ [W_dec_mu|W_dec_lv] + b -> bf16 ----
  gemm_bt<2><<<dim3(1024 / 128, B / 128), 256, 0, stream>>>(
      hbuf, Wt_dx, bdx, loglv, INV_16384, 0.f, B, 1024, H);
  // ---- softmax + log-likelihood ----
  lik_kernel<<<B / 32, 256, 0, stream>>>(loglv, x, acc);
  // ---- finalize mean ----
  fin_kernel<<<1, 1, 0, stream>>>(acc, (float*)d_out);
}

// Round 4
// 619.044 us; speedup vs baseline: 1.2490x; 1.0150x over previous
//
#include <hip/hip_runtime.h>

typedef unsigned char u8;
typedef unsigned short u16;
typedef unsigned int u32;
typedef long i64;
typedef __attribute__((ext_vector_type(2))) long long2v;
typedef __attribute__((ext_vector_type(4))) float floatx4;

#define LOG2PI_F 1.8378770664093453f

// ---------- helpers ----------
__device__ __forceinline__ u16 f2bf(float f) {
  union { float f; u32 i; } c; c.f = f;
  u32 i = c.i;
  u32 r = (i + 0x7fffu + ((i >> 16) & 1u)) >> 16;   // RNE (inputs finite)
  return (u16)r;
}
__device__ __forceinline__ float bf2f(u16 u) {
  union { u32 i; float f; } c; c.i = ((u32)u) << 16; return c.f;
}
__device__ __forceinline__ u8 f2fp8(float f) {
  int p = __builtin_amdgcn_cvt_pk_fp8_f32(f, f, 0, false);
  return (u8)(p & 0xff);
}
__device__ __forceinline__ u32 pk4fp8(float a, float b, float c, float d) {
  int lo = __builtin_amdgcn_cvt_pk_fp8_f32(a, b, 0, false);
  int v  = __builtin_amdgcn_cvt_pk_fp8_f32(c, d, lo, true);
  return (u32)v;
}
__device__ __forceinline__ void llds16(const void* g, void* l) {
  __builtin_amdgcn_global_load_lds(
      (const __attribute__((address_space(1))) u32*)g,
      (__attribute__((address_space(3))) u32*)l, 16, 0, 0);
}
// K-storage permutation: per 64-k group, octet order O0,O4,O1,O5,O2,O6,O3,O7
// so (h0,h1) octet pairs for quad q are the two 8B halves of 16B chunk q.
__device__ __forceinline__ u32 permk(u32 k) {
  u32 g = k & ~63u, o = (k >> 3) & 7u, r = k & 7u;
  u32 po = ((o & 3u) << 1) | (o >> 2);
  return g | (po << 3) | r;
}

// Scales (powers of 2; keep e4m3 out of subnormals):
//   x*16, weights*256, tanh-activations*64, z*16. Inverses folded into epilogues.
#define INV_4096  2.44140625e-4f
#define INV_16384 6.103515625e-5f

// ---------- packing kernels ----------
__global__ void pack_xb(const float* __restrict__ in, u32* __restrict__ out, int n4) {
  int i = blockIdx.x * 256 + threadIdx.x;
  if (i >= n4) return;
  const float4 v = ((const float4*)in)[i];
  int row = i >> 7;                    // D/4 = 128
  int k = (i & 127) << 2;
  int kp = permk(k);                   // float4 stays inside one octet
  out[(row << 7) + (kp >> 2)] = pk4fp8(v.x * 16.f, v.y * 16.f, v.z * 16.f, v.w * 16.f);
}

// W [K][N] fp32 -> Wt [N][permk(K)] fp8 (*256)
__global__ void pack_wt(const float* __restrict__ W, u8* __restrict__ Wt, int K, int N) {
  int idx = blockIdx.x * 256 + threadIdx.x;
  if (idx >= K * N) return;
  int k = idx / N, n = idx - k * N;
  Wt[(size_t)n * K + permk(k)] = f2fp8(W[idx] * 256.f);
}

// W1 [K][N1], W2 [K][N2] fp32 -> Wt [(N1+N2)][permk(K)] fp8 (*256)
__global__ void pack_wt2(const float* __restrict__ W1, const float* __restrict__ W2,
                         u8* __restrict__ Wt, int K, int N1, int N2) {
  int idx = blockIdx.x * 256 + threadIdx.x;
  if (idx >= (N1 + N2) * K) return;
  int n = idx / K, k = idx - n * K;
  float v = (n < N1) ? W1[(size_t)k * N1 + n] : W2[(size_t)k * N2 + (n - N1)];
  Wt[(size_t)n * K + permk(k)] = f2fp8(v * 256.f);
}

__global__ void catf(const float* __restrict__ a, const float* __restrict__ b,
                     float* __restrict__ o, int n1, int n2) {
  int i = blockIdx.x * 256 + threadIdx.x;
  if (i < n1) o[i] = a[i];
  else if (i < n1 + n2) o[i] = b[i - n1];
}

// ---------- fp8 MFMA GEMM: C = epi(A @ Bt^T * inv + bias) ----------
// A: [M][K] fp8 (K permuted), Bt: [N][K] fp8 (K permuted), bias: [N] f32. BK=64.
// Fragment reads are single ds_read_b128 (low 8B = h0 octet, high = h1 octet).
// EPI 0: tanh -> fp8*outs at permuted col ; 2: plain -> bf16 at natural col
template <int EPI>
__global__ __launch_bounds__(256) void gemm_bt(
    const u8* __restrict__ A, const u8* __restrict__ Bt,
    const float* __restrict__ bias, void* __restrict__ Cv,
    float inv, float outs, int M, int N, int K) {
  __shared__ __align__(16) u8 As[128 * 64];
  __shared__ __align__(16) u8 Bs[128 * 64];
  const int t = threadIdx.x;
  const int wave = t >> 6, lane = t & 63;
  const int quad = lane >> 4, l16 = lane & 15;
  const int bm = blockIdx.y * 128, bn = blockIdx.x * 128;
  const int wm = (wave >> 1) * 64, wn = (wave & 1) * 64;

  floatx4 acc[4][4];
#pragma unroll
  for (int i = 0; i < 4; ++i)
#pragma unroll
    for (int j = 0; j < 4; ++j) acc[i][j] = (floatx4){0.f, 0.f, 0.f, 0.f};

  for (int kt = 0; kt < K; kt += 64) {
#pragma unroll
    for (int i = 0; i < 2; ++i) {
      int c = i * 256 + t;
      int r = c >> 2, kcS = c & 3;
      int kc = kcS ^ ((r >> 1) & 3);
      llds16(A + (size_t)(bm + r) * K + kt + kc * 16, &As[c * 16]);
      llds16(Bt + (size_t)(bn + r) * K + kt + kc * 16, &Bs[c * 16]);
    }
    __builtin_amdgcn_s_waitcnt(0);
    __syncthreads();

    long2v a2[4], b2[4];
#pragma unroll
    for (int mi = 0; mi < 4; ++mi) {
      int m = wm + mi * 16 + l16;
      a2[mi] = *(const long2v*)&As[(4 * m + (quad ^ ((m >> 1) & 3))) * 16];
    }
#pragma unroll
    for (int ni = 0; ni < 4; ++ni) {
      int n = wn + ni * 16 + l16;
      b2[ni] = *(const long2v*)&Bs[(4 * n + (quad ^ ((n >> 1) & 3))) * 16];
    }
#pragma unroll
    for (int h = 0; h < 2; ++h)
#pragma unroll
      for (int mi = 0; mi < 4; ++mi)
#pragma unroll
        for (int ni = 0; ni < 4; ++ni)
          acc[mi][ni] = __builtin_amdgcn_mfma_f32_16x16x32_fp8_fp8(
              a2[mi][h], b2[ni][h], acc[mi][ni], 0, 0, 0);
    __syncthreads();
  }

  // epilogue: D[row=quad*4+r][col=lane&15]  (layout dtype-independent, m121-m128)
#pragma unroll
  for (int ni = 0; ni < 4; ++ni) {
    int col = bn + wn + ni * 16 + l16;
    float bv = bias[col];
#pragma unroll
    for (int mi = 0; mi < 4; ++mi) {
#pragma unroll
      for (int r = 0; r < 4; ++r) {
        int row = bm + wm + mi * 16 + quad * 4 + r;
        float v = acc[mi][ni][r] * inv + bv;
        if (EPI == 0) {
          ((u8*)Cv)[(size_t)row * N + permk(col)] = f2fp8(tanhf(v) * outs);
        } else {
          ((u16*)Cv)[(size_t)row * N + col] = f2bf(v);
        }
      }
    }
  }
}

// ---------- fused GEMM23 + reparameterise + KL (fp8) ----------
// A: [M][K] fp8 (h*64, K permuted), Bt: [128][K] fp8, bias [128].
// Cols 0..63 = mu_z, 64..127 = lv_z. Writes z [M][permk(64)] fp8 (*16).
__global__ __launch_bounds__(256) void gemm_z(
    const u8* __restrict__ A, const u8* __restrict__ Bt,
    const float* __restrict__ bias, const float* __restrict__ eps,
    u8* __restrict__ z, float* __restrict__ accp, int M, int K) {
  __shared__ __align__(16) u8 As[128 * 64];
  __shared__ __align__(16) u8 Bs[128 * 64];
  __shared__ float sexp[128 * 64];   // exp(0.5*lv) staging [row][col]
  const int t = threadIdx.x;
  const int wave = t >> 6, lane = t & 63;
  const int quad = lane >> 4, l16 = lane & 15;
  const int bm = blockIdx.y * 128;
  const int wm = (wave >> 1) * 64, wn = (wave & 1) * 64;

  floatx4 acc[4][4];
#pragma unroll
  for (int i = 0; i < 4; ++i)
#pragma unroll
    for (int j = 0; j < 4; ++j) acc[i][j] = (floatx4){0.f, 0.f, 0.f, 0.f};

  for (int kt = 0; kt < K; kt += 64) {
#pragma unroll
    for (int i = 0; i < 2; ++i) {
      int c = i * 256 + t;
      int r = c >> 2, kcS = c & 3;
      int kc = kcS ^ ((r >> 1) & 3);
      llds16(A + (size_t)(bm + r) * K + kt + kc * 16, &As[c * 16]);
      llds16(Bt + (size_t)r * K + kt + kc * 16, &Bs[c * 16]);
    }
    __builtin_amdgcn_s_waitcnt(0);
    __syncthreads();

    long2v a2[4], b2[4];
#pragma unroll
    for (int mi = 0; mi < 4; ++mi) {
      int m = wm + mi * 16 + l16;
      a2[mi] = *(const long2v*)&As[(4 * m + (quad ^ ((m >> 1) & 3))) * 16];
    }
#pragma unroll
    for (int ni = 0; ni < 4; ++ni) {
      int n = wn + ni * 16 + l16;
      b2[ni] = *(const long2v*)&Bs[(4 * n + (quad ^ ((n >> 1) & 3))) * 16];
    }
#pragma unroll
    for (int h = 0; h < 2; ++h)
#pragma unroll
      for (int mi = 0; mi < 4; ++mi)
#pragma unroll
        for (int ni = 0; ni < 4; ++ni)
          acc[mi][ni] = __builtin_amdgcn_mfma_f32_16x16x32_fp8_fp8(
              a2[mi][h], b2[ni][h], acc[mi][ni], 0, 0, 0);
    __syncthreads();
  }

  const bool is_lv = (wave & 1);
  float kl = 0.f;
#pragma unroll
  for (int ni = 0; ni < 4; ++ni) {
    int col = wn + ni * 16 + l16;            // 0..127
    float bv = bias[col];
#pragma unroll
    for (int mi = 0; mi < 4; ++mi) {
#pragma unroll
      for (int r = 0; r < 4; ++r) {
        int row = wm + mi * 16 + quad * 4 + r;   // 0..127 local
        float v = acc[mi][ni][r] * INV_16384 + bv;
        if (is_lv) {
          kl += 1.0f + v - __expf(v);
          sexp[row * 64 + (col - 64)] = __expf(0.5f * v);
        } else {
          kl -= v * v;
        }
      }
    }
  }
  __syncthreads();
  if (!is_lv) {
#pragma unroll
    for (int ni = 0; ni < 4; ++ni) {
      int col = wn + ni * 16 + l16;          // 0..63
      float bv = bias[col];
#pragma unroll
      for (int mi = 0; mi < 4; ++mi) {
#pragma unroll
        for (int r = 0; r < 4; ++r) {
          int row = wm + mi * 16 + quad * 4 + r;
          float mu = acc[mi][ni][r] * INV_16384 + bv;
          size_t grow = (size_t)(bm + row);
          float ep = eps[grow * 64 + col];
          z[grow * 64 + permk(col)] = f2fp8((mu + sexp[row * 64 + col] * ep) * 16.f);
        }
      }
    }
  }
  kl *= 0.5f;
  for (int off = 32; off > 0; off >>= 1) kl += __shfl_xor(kl, off, 64);
  __shared__ float s4[4];
  if (lane == 0) s4[wave] = kl;
  __syncthreads();
  if (t == 0) atomicAdd(accp, s4[0] + s4[1] + s4[2] + s4[3]);
}

// ---------- softmax + diag-Gaussian log-likelihood ----------
// loglv: [B][1024] bf16 (0..511 logits, 512..1023 lv_x); x: [B][512] f32
__global__ __launch_bounds__(256) void lik_kernel(
    const u16* __restrict__ loglv, const float* __restrict__ x,
    float* __restrict__ acc) {
  typedef __attribute__((ext_vector_type(8))) short short8;
  const int wave = threadIdx.x >> 6, lane = threadIdx.x & 63;
  float wacc = 0.f;
  for (int rr = 0; rr < 8; ++rr) {
    int row = blockIdx.x * 32 + wave * 8 + rr;
    const u16* Lr = loglv + (size_t)row * 1024;
    short8 lg8 = ((const short8*)Lr)[lane];
    float lg[8];
#pragma unroll
    for (int j = 0; j < 8; ++j) lg[j] = bf2f((u16)lg8[j]);
    float mx = lg[0];
#pragma unroll
    for (int j = 1; j < 8; ++j) mx = fmaxf(mx, lg[j]);
    for (int off = 32; off > 0; off >>= 1) mx = fmaxf(mx, __shfl_xor(mx, off, 64));
    float e[8], s = 0.f;
#pragma unroll
    for (int j = 0; j < 8; ++j) { e[j] = __expf(lg[j] - mx); s += e[j]; }
    for (int off = 32; off > 0; off >>= 1) s += __shfl_xor(s, off, 64);
    float inv_s = 1.0f / s;
    short8 lv8 = ((const short8*)Lr)[64 + lane];
    const float* xr = x + (size_t)row * 512 + lane * 8;
    float4 x0 = *(const float4*)xr, x1 = *(const float4*)(xr + 4);
    float xs[8] = {x0.x, x0.y, x0.z, x0.w, x1.x, x1.y, x1.z, x1.w};
    float T = 0.f;
#pragma unroll
    for (int j = 0; j < 8; ++j) {
      float lv = bf2f((u16)lv8[j]);
      float d = xs[j] - e[j] * inv_s;
      T += lv + d * d * __expf(-lv) + LOG2PI_F;
    }
    for (int off = 32; off > 0; off >>= 1) T += __shfl_xor(T, off, 64);
    if (lane == 0) wacc += -0.5f * T;
  }
  __shared__ float s4[4];
  if (lane == 0) s4[wave] = wacc;
  __syncthreads();
  if (threadIdx.x == 0) atomicAdd(acc, s4[0] + s4[1] + s4[2] + s4[3]);
}

__global__ void fin_kernel(const float* __restrict__ acc, float* __restrict__ out) {
  out[0] = acc[0] * (1.0f / 65536.0f);
}

// ---------- launch ----------
extern "C" void kernel_launch(void* const* d_in, const int* in_sizes, int n_in,
                              void* d_out, int out_size, void* d_ws, size_t ws_size,
                              hipStream_t stream) {
  const int B = 65536, D = 512, H = 1024, L = 64;
  const float* x       = (const float*)d_in[0];
  const float* eps     = (const float*)d_in[1];
  const float* W_enc_h = (const float*)d_in[2];
  const float* b_enc_h = (const float*)d_in[3];
  const float* W_enc_mu= (const float*)d_in[4];
  const float* b_enc_mu= (const float*)d_in[5];
  const float* W_enc_lv= (const float*)d_in[6];
  const float* b_enc_lv= (const float*)d_in[7];
  const float* W_dec_h = (const float*)d_in[8];
  const float* b_dec_h = (const float*)d_in[9];
  const float* W_dec_mu= (const float*)d_in[10];
  const float* b_dec_mu= (const float*)d_in[11];
  const float* W_dec_lv= (const float*)d_in[12];
  const float* b_dec_lv= (const float*)d_in[13];

  char* ws = (char*)d_ws;
  // weights (fp8) / bias / acc block
  u8*   Wt_eh  = (u8*)(ws + 0);             // [1024][512]  512K
  u8*   Wt_z   = (u8*)(ws + 524288);        // [128][1024]  128K
  u8*   Wt_dh  = (u8*)(ws + 655360);        // [1024][64]    64K
  u8*   Wt_dx  = (u8*)(ws + 720896);        // [1024][1024]   1M
  float* bh    = (float*)(ws + 2097152);    // [1024]
  float* bz    = (float*)(ws + 2101248);    // [128]
  float* bdh   = (float*)(ws + 2105344);    // [1024]
  float* bdx   = (float*)(ws + 2109440);    // [1024]
  float* acc   = (float*)(ws + 2113536);    // [1]
  // big regions (peak 232 MB)
  u8*   hbuf   = (u8*)(ws + 4194304);       // [B][1024] fp8: h then hd (64MB)
  u8*   xb     = (u8*)(ws + 71303168);      // [B][512] fp8 (32MB, dead after GEMM1)
  u8*   zbuf   = (u8*)(ws + 104857600);     // [B][64] fp8 (4MB, dead after GEMM4)
  u16*  loglv  = (u16*)(ws + 109051904);    // [B][1024] bf16 (128MB)

  hipMemsetAsync(acc, 0, 256, stream);

  // ---- packing ----
  pack_xb<<<(B * D / 4 + 255) / 256, 256, 0, stream>>>(x, (u32*)xb, B * D / 4);
  pack_wt<<<(D * H + 255) / 256, 256, 0, stream>>>(W_enc_h, Wt_eh, D, H);
  pack_wt2<<<(H * 2 * L + 255) / 256, 256, 0, stream>>>(W_enc_mu, W_enc_lv, Wt_z, H, L, L);
  pack_wt<<<(L * H + 255) / 256, 256, 0, stream>>>(W_dec_h, Wt_dh, L, H);
  pack_wt2<<<(H * 2 * D + 255) / 256, 256, 0, stream>>>(W_dec_mu, W_dec_lv, Wt_dx, H, D, D);
  catf<<<(H + 255) / 256, 256, 0, stream>>>(b_enc_h, b_enc_h, bh, H, 0);
  catf<<<(2 * L + 255) / 256, 256, 0, stream>>>(b_enc_mu, b_enc_lv, bz, L, L);
  catf<<<(H + 255) / 256, 256, 0, stream>>>(b_dec_h, b_dec_h, bdh, H, 0);
  catf<<<(2 * D + 255) / 256, 256, 0, stream>>>(b_dec_mu, b_dec_lv, bdx, D, D);

  // ---- encoder: h = tanh(x @ W_enc_h + b), h stored fp8*64, K-permuted ----
  gemm_bt<0><<<dim3(H / 128, B / 128), 256, 0, stream>>>(
      xb, Wt_eh, bh, hbuf, INV_4096, 64.f, B, H, D);
  // ---- fused: mu|lv = h @ Wt_z + b ; z = mu + exp(.5 lv) eps (fp8*16) ; KL ----
  gemm_z<<<dim3(1, B / 128), 256, 0, stream>>>(hbuf, Wt_z, bz, eps, zbuf, acc, B, H);
  // ---- decoder hidden: hd = tanh(z @ W_dec_h + b), fp8*64 (overwrites hbuf) ----
  gemm_bt<0><<<dim3(H / 128, B / 128), 256, 0, stream>>>(
      zbuf, Wt_dh, bdh, hbuf, INV_4096, 64.f, B, H, L);
  // ---- logits | lv_x = hd @ [W_dec_mu|W_dec_lv] + b -> bf16 (natural col order) ----
  gemm_bt<2><<<dim3(1024 / 128, B / 128), 256, 0, stream>>>(
      hbuf, Wt_dx, bdx, loglv, INV_16384, 0.f, B, 1024, H);
  // ---- softmax + log-likelihood ----
  lik_kernel<<<B / 32, 256, 0, stream>>>(loglv, x, acc);
  // ---- finalize mean ----
  fin_kernel<<<1, 1, 0, stream>>>(acc, (float*)d_out);
}